// Round 2
// baseline (1105.227 us; speedup 1.0000x reference)
//
#include <hip/hip_runtime.h>
#include <hip/hip_bf16.h>

// ModulatedConv2D: B=16, CIN=512, COUT=512, H=W=32, K=3, WDIM=512
//
// Decomposition:
//   style[b][c]  = w_latent[b,:] @ dense_kernel[:,c] + bias[c]          [16][512]
//   S[kh][cin]   = sum_{kw,cout} conv_w[kh,kw,cin,cout]^2               [3][512]
//   denom[b][kh] = rsqrt( sum_cin S[kh][cin] * style[b][cin]^2 )        [16][3]
//   out[(b,y,x)][cout] = sum_{kh,kw,cin} img[b,cin,y+kh-1,x+kw-1]
//                         * style[b,cin] * denom[b,kh] * conv_w[kh,kw,cin,cout]
// i.e. implicit GEMM  M=16384 (b,y,x), N=512 (cout), K=4608 (kh,kw,cin),
// with W = conv_weights viewed as [4608][512] row-major (no transform).

#define BM 128
#define BN 128
#define BK 16

__global__ void style_kernel(const float* __restrict__ wl,
                             const float* __restrict__ dk,
                             const float* __restrict__ bias,
                             float* __restrict__ style) {
    int gid = blockIdx.x * 256 + threadIdx.x;   // 0..8191
    int b = gid >> 9, c = gid & 511;
    float acc = bias[c];
    const float* wrow = wl + b * 512;
    #pragma unroll 4
    for (int k = 0; k < 512; ++k)
        acc = fmaf(wrow[k], dk[k * 512 + c], acc);
    style[gid] = acc;
}

__global__ void wsum_kernel(const float* __restrict__ cw, float* __restrict__ S) {
    int bid = blockIdx.x;            // kh*512 + cin
    int kh = bid >> 9, cin = bid & 511;
    int lane = threadIdx.x;          // 0..63 (one wave)
    float acc = 0.f;
    #pragma unroll
    for (int kw = 0; kw < 3; ++kw) {
        const float* p = cw + ((size_t)((kh * 3 + kw) << 9) + cin) * 512;
        for (int co = lane; co < 512; co += 64) {
            float v = p[co];
            acc = fmaf(v, v, acc);
        }
    }
    #pragma unroll
    for (int off = 32; off; off >>= 1) acc += __shfl_down(acc, off);
    if (lane == 0) S[bid] = acc;
}

__global__ void denom_kernel(const float* __restrict__ S,
                             const float* __restrict__ style,
                             float* __restrict__ dn) {
    int bid = blockIdx.x;            // b*3 + kh
    int b = bid / 3, kh = bid % 3;
    int lane = threadIdx.x;
    float acc = 0.f;
    for (int c = lane; c < 512; c += 64) {
        float s = style[b * 512 + c];
        acc = fmaf(S[kh * 512 + c], s * s, acc);
    }
    #pragma unroll
    for (int off = 32; off; off >>= 1) acc += __shfl_down(acc, off);
    if (lane == 0) dn[bid] = rsqrtf(acc);
}

__global__ __launch_bounds__(256) void conv_gemm(
    const float* __restrict__ img,    // [16][512][32][32]
    const float* __restrict__ cw,     // [4608][512]
    const float* __restrict__ style,  // [16][512]
    const float* __restrict__ dn,     // [16][3]
    float* __restrict__ out)          // [16][512][32][32]
{
    __shared__ float As[BK][BM];
    __shared__ float Bs[BK][BN];

    const int tid = threadIdx.x;
    const int bm0 = blockIdx.x * BM;          // M offset (multiple of 128)
    const int bn0 = blockIdx.y * BN;          // N offset
    const int b   = bm0 >> 10;                // batch index: constant per block
    const int m_base = bm0 & 1023;            // pixel base (y*32+x)

    const int tx = tid & 15;                  // -> N
    const int ty = tid >> 4;                  // -> M

    // A staging: thread loads 8 elems, m = tid&127 fixed, k = (tid>>7)*8 + i
    const int a_m  = tid & 127;
    const int a_k0 = (tid >> 7) * 8;
    const int gy = (m_base + a_m) >> 5;
    const int gx = (m_base + a_m) & 31;

    // B staging: two float4 rows
    const int b_row = tid >> 5;               // 0..7 (and +8)
    const int b_col = (tid & 31) * 4;

    const float d0 = dn[b * 3 + 0];
    const float d1 = dn[b * 3 + 1];
    const float d2 = dn[b * 3 + 2];

    float acc[8][8];
    #pragma unroll
    for (int i = 0; i < 8; ++i)
        #pragma unroll
        for (int j = 0; j < 8; ++j) acc[i][j] = 0.f;

    const float* imgb = img + (size_t)(b << 9) * 1024;  // this batch's image
    const float* stb  = style + (b << 9);

    for (int k0 = 0; k0 < 4608; k0 += BK) {
        // ---- stage B tile: [16][128] of conv_w ----
        {
            const float4 g0 = *(const float4*)&cw[(size_t)(k0 + b_row) * 512 + bn0 + b_col];
            const float4 g1 = *(const float4*)&cw[(size_t)(k0 + b_row + 8) * 512 + bn0 + b_col];
            *(float4*)&Bs[b_row][b_col]     = g0;
            *(float4*)&Bs[b_row + 8][b_col] = g1;
        }
        // ---- stage A tile: [16][128] of scaled im2col ----
        #pragma unroll
        for (int i = 0; i < 8; ++i) {
            int kg  = k0 + a_k0 + i;          // global K index (wave-uniform)
            int cin = kg & 511;
            int kwh = kg >> 9;                // 0..8 = kh*3+kw
            int kh  = kwh >= 6 ? 2 : (kwh >= 3 ? 1 : 0);
            int kw  = kwh - kh * 3;
            int yy = gy + kh - 1;
            int xx = gx + kw - 1;
            float v = 0.f;
            if ((unsigned)yy < 32u && (unsigned)xx < 32u) {
                float dd = (kh == 0) ? d0 : (kh == 1 ? d1 : d2);
                v = imgb[(size_t)cin * 1024 + yy * 32 + xx] * stb[cin] * dd;
            }
            As[a_k0 + i][a_m] = v;
        }
        __syncthreads();

        // ---- compute ----
        #pragma unroll
        for (int k = 0; k < BK; ++k) {
            float4 a0 = *(const float4*)&As[k][ty * 4];
            float4 a1 = *(const float4*)&As[k][64 + ty * 4];
            float4 b0 = *(const float4*)&Bs[k][tx * 4];
            float4 b1 = *(const float4*)&Bs[k][64 + tx * 4];
            float ar[8] = {a0.x, a0.y, a0.z, a0.w, a1.x, a1.y, a1.z, a1.w};
            float br[8] = {b0.x, b0.y, b0.z, b0.w, b1.x, b1.y, b1.z, b1.w};
            #pragma unroll
            for (int i = 0; i < 8; ++i)
                #pragma unroll
                for (int j = 0; j < 8; ++j)
                    acc[i][j] = fmaf(ar[i], br[j], acc[i][j]);
        }
        __syncthreads();
    }

    // ---- store: out[b][bn0+c][m_base + r] ----
    const int ch_base = (b << 9) + bn0;
    #pragma unroll
    for (int j = 0; j < 8; ++j) {
        int c = (j < 4) ? (tx * 4 + j) : (64 + tx * 4 + (j - 4));
        float* op = out + (size_t)(ch_base + c) * 1024 + m_base;
        #pragma unroll
        for (int i = 0; i < 8; ++i) {
            int r = (i < 4) ? (ty * 4 + i) : (64 + ty * 4 + (i - 4));
            op[r] = acc[i][j];
        }
    }
}

extern "C" void kernel_launch(void* const* d_in, const int* in_sizes, int n_in,
                              void* d_out, int out_size, void* d_ws, size_t ws_size,
                              hipStream_t stream) {
    const float* img  = (const float*)d_in[0];   // [16][512][32][32]
    const float* wl   = (const float*)d_in[1];   // [16][512]
    const float* dk   = (const float*)d_in[2];   // [512][512]
    const float* bias = (const float*)d_in[3];   // [512]
    const float* cw   = (const float*)d_in[4];   // [3][3][512][512]
    float* out = (float*)d_out;

    float* style = (float*)d_ws;                 // 8192 floats
    float* S     = style + 8192;                 // 1536 floats
    float* dn    = S + 1536;                     // 48 floats

    style_kernel<<<32, 256, 0, stream>>>(wl, dk, bias, style);
    wsum_kernel<<<1536, 64, 0, stream>>>(cw, S);
    denom_kernel<<<48, 64, 0, stream>>>(S, style, dn);

    dim3 grid(16384 / BM, 512 / BN);             // (128, 4)
    conv_gemm<<<grid, 256, 0, stream>>>(img, cw, style, dn, out);
}

// Round 4
// 416.425 us; speedup vs baseline: 2.6541x; 2.6541x over previous
//
#include <hip/hip_runtime.h>
#include <hip/hip_bf16.h>

// ModulatedConv2D (B=16, CIN=COUT=512, H=W=32, K=3) via bf16-split implicit GEMM.
//
//   style[b][c]  = w_latent[b,:] @ dense_kernel[:,c] + bias[c]
//   S[kh][cin]   = sum_{kw,cout} conv_w[kh,kw,cin,cout]^2
//   denom[b][kh] = rsqrt( sum_cin S[kh][cin] * style[b][cin]^2 )
//   out[b,co,p]  = sum_k  W[k][co] * (img[b,cin,p+shift] * style[b,cin]) * denom[b,kh]
//
// GEMM: M=cout(512), N=pixels per batch (1024), K=4608, batch b fixed per block.
// fp32 emulated as bf16 hi/lo: C = Whi*Ihi + Whi*Ilo + Wlo*Ihi  (3 MFMA passes).
// denom folded via exact accumulator rescale at kh-segment boundaries.
//
// ws layout: style[8192]f32 | S[1536]f32 | dn[48]f32 | pad | WThi[512][4608]bf16 | WTlo
// ws bytes needed ~= 9.5 MB.

typedef short short8 __attribute__((ext_vector_type(8)));
typedef float f32x4 __attribute__((ext_vector_type(4)));

#define LDK 40          // padded LDS K-stride (elems); 80 B rows -> 2-way bank (free)

__device__ __forceinline__ ushort bf16_rtne(float f) {
    unsigned u = __float_as_uint(f);
    unsigned r = u + 0x7fffu + ((u >> 16) & 1u);
    return (ushort)(r >> 16);
}
__device__ __forceinline__ float bf16_up(ushort h) {
    return __uint_as_float(((unsigned)h) << 16);
}

__global__ void style_kernel(const float* __restrict__ wl,
                             const float* __restrict__ dk,
                             const float* __restrict__ bias,
                             float* __restrict__ style) {
    int gid = blockIdx.x * 256 + threadIdx.x;   // 0..8191
    int b = gid >> 9, c = gid & 511;
    float acc = bias[c];
    const float* wrow = wl + b * 512;
    #pragma unroll 4
    for (int k = 0; k < 512; ++k)
        acc = fmaf(wrow[k], dk[k * 512 + c], acc);
    style[gid] = acc;
}

__global__ void wsum_kernel(const float* __restrict__ cw, float* __restrict__ S) {
    int bid = blockIdx.x;            // kh*512 + cin
    int kh = bid >> 9, cin = bid & 511;
    int lane = threadIdx.x;          // one wave
    float acc = 0.f;
    #pragma unroll
    for (int kw = 0; kw < 3; ++kw) {
        const float* p = cw + ((size_t)((kh * 3 + kw) << 9) + cin) * 512;
        for (int co = lane; co < 512; co += 64) {
            float v = p[co];
            acc = fmaf(v, v, acc);
        }
    }
    #pragma unroll
    for (int off = 32; off; off >>= 1) acc += __shfl_down(acc, off);
    if (lane == 0) S[bid] = acc;
}

__global__ void denom_kernel(const float* __restrict__ S,
                             const float* __restrict__ style,
                             float* __restrict__ dn) {
    int bid = blockIdx.x;            // b*3 + kh
    int b = bid / 3, kh = bid % 3;
    int lane = threadIdx.x;
    float acc = 0.f;
    for (int c = lane; c < 512; c += 64) {
        float s = style[b * 512 + c];
        acc = fmaf(S[kh * 512 + c], s * s, acc);
    }
    #pragma unroll
    for (int off = 32; off; off >>= 1) acc += __shfl_down(acc, off);
    if (lane == 0) dn[bid] = rsqrtf(acc);
}

// Transpose + split conv_weights [4608][512] f32 -> WThi/WTlo [512][4608] bf16.
__global__ __launch_bounds__(256) void wsplit_kernel(const float* __restrict__ cw,
                                                     ushort* __restrict__ wthi,
                                                     ushort* __restrict__ wtlo) {
    __shared__ ushort hs[64][72];
    __shared__ ushort ls[64][72];
    int t = threadIdx.x;
    int k0 = blockIdx.x * 64, c0 = blockIdx.y * 64;
    int col = t & 63;
    int rq = t >> 6;                 // 0..3
    #pragma unroll
    for (int i = 0; i < 16; ++i) {
        int kr = rq * 16 + i;
        float v = cw[(size_t)(k0 + kr) * 512 + c0 + col];
        ushort hh = bf16_rtne(v);
        ushort ll = bf16_rtne(v - bf16_up(hh));
        hs[col][kr] = hh;            // transpose on write
        ls[col][kr] = ll;
    }
    __syncthreads();
    int r = t >> 2, kq = (t & 3) << 4;
    size_t o = (size_t)(c0 + r) * 4608 + k0 + kq;
    *(uint4*)&wthi[o]     = *(const uint4*)&hs[r][kq];
    *(uint4*)&wthi[o + 8] = *(const uint4*)&hs[r][kq + 8];
    *(uint4*)&wtlo[o]     = *(const uint4*)&ls[r][kq];
    *(uint4*)&wtlo[o + 8] = *(const uint4*)&ls[r][kq + 8];
}

// Main conv GEMM. Block tile: 128 cout x 128 pix, BK=32, 4 waves (2x2), wave tile 64x64.
__global__ __launch_bounds__(256) void conv_gemm(
    const float*  __restrict__ img,    // [16][512][32][32]
    const ushort* __restrict__ wthi,   // [512][4608] bf16
    const ushort* __restrict__ wtlo,
    const float*  __restrict__ style,  // [16][512]
    const float*  __restrict__ dn,     // [16][3]
    float* __restrict__ out)           // [16][512][32][32]
{
    __shared__ ushort Wl[2][128][LDK]; // [hi/lo][cout][k]
    __shared__ ushort Il[2][128][LDK]; // [hi/lo][pix ][k]
    __shared__ float  styl[512];
    __shared__ float  dsh[3];

    const int tid  = threadIdx.x;
    const int lane = tid & 63;
    const int wid  = tid >> 6;

    const int pixblk  = blockIdx.x;            // 0..127
    const int coutblk = blockIdx.y;            // 0..3
    const int b        = pixblk >> 3;
    const int pix_base = (pixblk & 7) * 128;
    const int cout_base = coutblk * 128;

    const int wr = (wid >> 1) * 64;            // wave cout-offset
    const int wc = (wid & 1) * 64;             // wave pix-offset

    // image staging geometry: thread owns one pixel, 16 contiguous k
    const int lm      = tid & 127;             // local pixel
    const int khalf16 = (tid >> 7) * 16;       // k sub-range 0 or 16
    const int pix = pix_base + lm;
    const int y = pix >> 5, x = pix & 31;

    // W staging geometry
    const int wrow = tid >> 1;
    const int wk16 = (tid & 1) << 4;

    for (int i = tid; i < 512; i += 256) styl[i] = style[(b << 9) + i];
    if (tid < 3) dsh[tid] = dn[b * 3 + tid];
    __syncthreads();

    f32x4 acc[4][4];
    #pragma unroll
    for (int i = 0; i < 4; ++i)
        #pragma unroll
        for (int j = 0; j < 4; ++j) acc[i][j] = (f32x4)0.f;

    const int rl = lane & 15;
    const int kg = (lane >> 4) << 3;

    int k0 = 0;
    for (int seg = 0; seg < 3; ++seg) {
        for (int s = 0; s < 48; ++s, k0 += 32) {
            // ---- step-uniform geometry ----
            const int khw = k0 >> 9;                 // 0..8
            const int kh  = khw >= 6 ? 2 : (khw >= 3 ? 1 : 0);
            const int kw  = khw - kh * 3;
            const int dy = kh - 1, dx = kw - 1;
            const int cin0 = k0 & 511;
            const int yy = y + dy, xx = x + dx;
            const bool vld = ((unsigned)yy < 32u) && ((unsigned)xx < 32u);
            const int yc = min(max(yy, 0), 31), xc = min(max(xx, 0), 31);
            const int off = (yc << 5) + xc;
            const float sv = vld ? 1.f : 0.f;

            // ---- stage W tile (pure bf16 copy) ----
            {
                size_t o = (size_t)(cout_base + wrow) * 4608 + k0 + wk16;
                *(uint4*)&Wl[0][wrow][wk16]     = *(const uint4*)&wthi[o];
                *(uint4*)&Wl[0][wrow][wk16 + 8] = *(const uint4*)&wthi[o + 8];
                *(uint4*)&Wl[1][wrow][wk16]     = *(const uint4*)&wtlo[o];
                *(uint4*)&Wl[1][wrow][wk16 + 8] = *(const uint4*)&wtlo[o + 8];
            }
            // ---- stage I tile (load f32, scale by style, split) ----
            {
                const int cinb = cin0 + khalf16;
                const float* ip = img + ((size_t)(b << 9) + cinb) * 1024;
                union { ushort u[16]; uint4 v[2]; } hb, lb;
                #pragma unroll
                for (int i = 0; i < 16; ++i) {
                    float sc = styl[cinb + i] * sv;
                    float v  = ip[(size_t)i * 1024 + off] * sc;
                    ushort hh = bf16_rtne(v);
                    hb.u[i] = hh;
                    lb.u[i] = bf16_rtne(v - bf16_up(hh));
                }
                *(uint4*)&Il[0][lm][khalf16]     = hb.v[0];
                *(uint4*)&Il[0][lm][khalf16 + 8] = hb.v[1];
                *(uint4*)&Il[1][lm][khalf16]     = lb.v[0];
                *(uint4*)&Il[1][lm][khalf16 + 8] = lb.v[1];
            }
            __syncthreads();

            // ---- fragments + MFMA ----
            {
                short8 wa0[4], wa1[4], ib0[4], ib1[4];
                #pragma unroll
                for (int mi = 0; mi < 4; ++mi) {
                    wa0[mi] = *(const short8*)&Wl[0][wr + mi * 16 + rl][kg];
                    wa1[mi] = *(const short8*)&Wl[1][wr + mi * 16 + rl][kg];
                }
                #pragma unroll
                for (int ni = 0; ni < 4; ++ni) {
                    ib0[ni] = *(const short8*)&Il[0][wc + ni * 16 + rl][kg];
                    ib1[ni] = *(const short8*)&Il[1][wc + ni * 16 + rl][kg];
                }
                #pragma unroll
                for (int mi = 0; mi < 4; ++mi)
                    #pragma unroll
                    for (int ni = 0; ni < 4; ++ni) {
                        acc[mi][ni] = __builtin_amdgcn_mfma_f32_16x16x32_bf16(
                            wa0[mi], ib0[ni], acc[mi][ni], 0, 0, 0);
                        acc[mi][ni] = __builtin_amdgcn_mfma_f32_16x16x32_bf16(
                            wa0[mi], ib1[ni], acc[mi][ni], 0, 0, 0);
                        acc[mi][ni] = __builtin_amdgcn_mfma_f32_16x16x32_bf16(
                            wa1[mi], ib0[ni], acc[mi][ni], 0, 0, 0);
                    }
            }
            __syncthreads();
        }
        if (seg < 2) {
            // exact denom fold: running acc currently holds partial for segs<=seg
            // scaled by d[seg]; convert to d[seg+1] basis.
            float rr = dsh[seg] / dsh[seg + 1];
            #pragma unroll
            for (int mi = 0; mi < 4; ++mi)
                #pragma unroll
                for (int ni = 0; ni < 4; ++ni) acc[mi][ni] *= rr;
        }
    }

    // ---- epilogue: scale by d[2], store ----
    const float dlast = dsh[2];
    #pragma unroll
    for (int mi = 0; mi < 4; ++mi) {
        const int crow = cout_base + wr + mi * 16 + ((lane >> 4) << 2);
        #pragma unroll
        for (int ni = 0; ni < 4; ++ni) {
            const int ccol = pix_base + wc + ni * 16 + (lane & 15);
            float* op = out + ((size_t)(b << 9) + crow) * 1024 + ccol;
            f32x4 c = acc[mi][ni];
            #pragma unroll
            for (int r = 0; r < 4; ++r)
                op[(size_t)r * 1024] = c[r] * dlast;
        }
    }
}

extern "C" void kernel_launch(void* const* d_in, const int* in_sizes, int n_in,
                              void* d_out, int out_size, void* d_ws, size_t ws_size,
                              hipStream_t stream) {
    const float* img  = (const float*)d_in[0];   // [16][512][32][32]
    const float* wl   = (const float*)d_in[1];   // [16][512]
    const float* dk   = (const float*)d_in[2];   // [512][512]
    const float* bias = (const float*)d_in[3];   // [512]
    const float* cw   = (const float*)d_in[4];   // [3][3][512][512]
    float* out = (float*)d_out;

    float* style = (float*)d_ws;                           // 8192 f32
    float* S     = style + 8192;                           // 1536 f32
    float* dn    = S + 1536;                               // 48 f32
    ushort* wthi = (ushort*)((char*)d_ws + 40960);         // [512][4608] bf16
    ushort* wtlo = wthi + (size_t)512 * 4608;

    style_kernel<<<32, 256, 0, stream>>>(wl, dk, bias, style);
    wsum_kernel<<<1536, 64, 0, stream>>>(cw, S);
    denom_kernel<<<48, 64, 0, stream>>>(S, style, dn);
    wsplit_kernel<<<dim3(72, 8), 256, 0, stream>>>(cw, wthi, wtlo);

    conv_gemm<<<dim3(128, 4), 256, 0, stream>>>(img, wthi, wtlo, style, dn, out);
}

// Round 5
// 329.631 us; speedup vs baseline: 3.3529x; 1.2633x over previous
//
#include <hip/hip_runtime.h>
#include <hip/hip_bf16.h>

// ModulatedConv2D (B=16, CIN=COUT=512, H=W=32, K=3) — bf16-split implicit GEMM v2.
//
// Precompute (once per launch):
//   style[b][c]   = w_latent[b,:]@dense_kernel[:,c] + bias
//   denom[b][kh]  = rsqrt(sum_cin S[kh][cin]*style^2),  S = sum_{kw,cout} cw^2
//   WT2hi/lo [cb=4][step=144][row=128][kk=32]  = tiled transposed split conv_w
//   Itrhi/lo [b=16][yp=34][xp=34][cin=512]     = zero-halo transposed split (img*style)
// Hot loop (conv_gemm): pure-copy staging via global_load_lds(16B) into unpadded
// [128][32] LDS tiles; 48 MFMA + 16 ds_read_b128 + 8 gld_lds per wave-step;
// C = Whi*Ihi + Whi*Ilo + Wlo*Ihi; denom folded by exact acc rescale per kh-segment.
//
// ws layout: style 32KB | S,dn | @64KB: WT2hi(4.72MB) WT2lo Itrhi(18.9MB) Itrlo
// TOTAL ws needed = 47,382,528 B (~45.2 MB).

typedef short short8 __attribute__((ext_vector_type(8)));
typedef float f32x4 __attribute__((ext_vector_type(4)));

__device__ __forceinline__ ushort bf16_rtne(float f) {
    unsigned u = __float_as_uint(f);
    unsigned r = u + 0x7fffu + ((u >> 16) & 1u);
    return (ushort)(r >> 16);
}
__device__ __forceinline__ float bf16_up(ushort h) {
    return __uint_as_float(((unsigned)h) << 16);
}
__device__ __forceinline__ void gld16(const void* g, void* l) {
    __builtin_amdgcn_global_load_lds(
        (const __attribute__((address_space(1))) unsigned int*)g,
        (__attribute__((address_space(3))) unsigned int*)l, 16, 0, 0);
}

// ---- style: [16][512] = wl @ dk + bias, k split 4-way for latency ----
__global__ __launch_bounds__(256) void style_kernel(const float* __restrict__ wl,
                                                    const float* __restrict__ dk,
                                                    const float* __restrict__ bias,
                                                    float* __restrict__ style) {
    __shared__ float wsh[512];
    __shared__ float red[4][64];
    const int b = blockIdx.y, c0 = blockIdx.x * 64, t = threadIdx.x;
    for (int i = t; i < 512; i += 256) wsh[i] = wl[b * 512 + i];
    __syncthreads();
    const int c = c0 + (t & 63), kq = (t >> 6) * 128;
    float acc = 0.f;
    #pragma unroll 8
    for (int k = 0; k < 128; ++k)
        acc = fmaf(wsh[kq + k], dk[(size_t)(kq + k) * 512 + c], acc);
    red[t >> 6][t & 63] = acc;
    __syncthreads();
    if (t < 64)
        style[b * 512 + c0 + t] =
            red[0][t] + red[1][t] + red[2][t] + red[3][t] + bias[c0 + t];
}

__global__ void wsum_kernel(const float* __restrict__ cw, float* __restrict__ S) {
    int bid = blockIdx.x;            // kh*512 + cin
    int kh = bid >> 9, cin = bid & 511;
    int lane = threadIdx.x;
    float acc = 0.f;
    #pragma unroll
    for (int kw = 0; kw < 3; ++kw) {
        const float* p = cw + ((size_t)((kh * 3 + kw) << 9) + cin) * 512;
        for (int co = lane; co < 512; co += 64) {
            float v = p[co];
            acc = fmaf(v, v, acc);
        }
    }
    #pragma unroll
    for (int off = 32; off; off >>= 1) acc += __shfl_down(acc, off);
    if (lane == 0) S[bid] = acc;
}

__global__ void denom_kernel(const float* __restrict__ S,
                             const float* __restrict__ style,
                             float* __restrict__ dn) {
    int bid = blockIdx.x;            // b*3 + kh
    int b = bid / 3, kh = bid % 3;
    int lane = threadIdx.x;
    float acc = 0.f;
    for (int c = lane; c < 512; c += 64) {
        float s = style[b * 512 + c];
        acc = fmaf(S[kh * 512 + c], s * s, acc);
    }
    #pragma unroll
    for (int off = 32; off; off >>= 1) acc += __shfl_down(acc, off);
    if (lane == 0) dn[bid] = rsqrtf(acc);
}

// ---- conv_w [4608][512] f32 -> tiled split WT2 [cb][step][row][kk] bf16 ----
__global__ __launch_bounds__(256) void wsplit_kernel(const float* __restrict__ cw,
                                                     ushort* __restrict__ wthi,
                                                     ushort* __restrict__ wtlo) {
    __shared__ ushort hs[64][72];
    __shared__ ushort ls[64][72];
    int t = threadIdx.x;
    int k0 = blockIdx.x * 64, c0 = blockIdx.y * 64;
    int col = t & 63;
    int rq = t >> 6;
    #pragma unroll
    for (int i = 0; i < 16; ++i) {
        int kr = rq * 16 + i;
        float v = cw[(size_t)(k0 + kr) * 512 + c0 + col];
        ushort hh = bf16_rtne(v);
        ushort ll = bf16_rtne(v - bf16_up(hh));
        hs[col][kr] = hh;            // transpose on write
        ls[col][kr] = ll;
    }
    __syncthreads();
    int r = t >> 2, kq = (t & 3) << 4;        // kq in {0,16,32,48}
    int cout = c0 + r;
    int k = k0 + kq;
    // tiled: [(cout>>7)][k>>5][cout&127][k&31]
    size_t o = ((size_t)(cout >> 7) * 144 + (k >> 5)) * 4096 +
               (size_t)(cout & 127) * 32 + (k & 31);
    *(uint4*)&wthi[o]     = *(const uint4*)&hs[r][kq];
    *(uint4*)&wthi[o + 8] = *(const uint4*)&hs[r][kq + 8];
    *(uint4*)&wtlo[o]     = *(const uint4*)&ls[r][kq];
    *(uint4*)&wtlo[o + 8] = *(const uint4*)&ls[r][kq + 8];
}

// ---- img [16][512][32][32] f32 -> zero-halo split (img*style) [16][34][34][512] ----
__global__ __launch_bounds__(256) void isplit_kernel(const float* __restrict__ img,
                                                     const float* __restrict__ style,
                                                     ushort* __restrict__ ihi,
                                                     ushort* __restrict__ ilo) {
    const int b = blockIdx.y, yp = blockIdx.x, t = threadIdx.x;
    const size_t rowbase = (size_t)(b * 34 + yp) * 34 * 512;
    uint4 z = {0u, 0u, 0u, 0u};
    if (yp == 0 || yp == 33) {           // zero full row (34*512 shorts = 2176 uint4)
        for (int i = t; i < 2176; i += 256) {
            ((uint4*)(ihi + rowbase))[i] = z;
            ((uint4*)(ilo + rowbase))[i] = z;
        }
        return;
    }
    if (t < 64) {                        // zero xp=0 and xp=33 columns
        ((uint4*)(ihi + rowbase))[t] = z;
        ((uint4*)(ilo + rowbase))[t] = z;
        ((uint4*)(ihi + rowbase + 33 * 512))[t] = z;
        ((uint4*)(ilo + rowbase + 33 * 512))[t] = z;
    }
    const int y = yp - 1;
    __shared__ float buf[64][33];
    const int ci = t >> 5, x = t & 31;       // load role
    const int xo = t >> 3, cs = (t & 7) * 8; // store role
    for (int c0 = 0; c0 < 512; c0 += 64) {
        __syncthreads();
        #pragma unroll
        for (int i = 0; i < 8; ++i) {
            int cin = c0 + ci + i * 8;
            float v = img[((size_t)(b * 512 + cin) * 32 + y) * 32 + x] *
                      style[b * 512 + cin];
            buf[ci + i * 8][x] = v;
        }
        __syncthreads();
        union { ushort u[8]; uint4 v; } hb, lb;
        #pragma unroll
        for (int i = 0; i < 8; ++i) {
            float v = buf[cs + i][xo];
            ushort hh = bf16_rtne(v);
            hb.u[i] = hh;
            lb.u[i] = bf16_rtne(v - bf16_up(hh));
        }
        size_t o = rowbase + (size_t)(xo + 1) * 512 + c0 + cs;
        *(uint4*)&ihi[o] = hb.v;
        *(uint4*)&ilo[o] = lb.v;
    }
}

// ---- main GEMM: 128 cout x 128 pix block, BK=32, 4 waves (2x2), 64x64/wave ----
__global__ __launch_bounds__(256) void conv_gemm(
    const ushort* __restrict__ wt2hi,  // [4][144][128][32]
    const ushort* __restrict__ wt2lo,
    const ushort* __restrict__ ihi,    // [16][34][34][512]
    const ushort* __restrict__ ilo,
    const float*  __restrict__ dn,     // [16][3]
    float* __restrict__ out)           // [16][512][32][32]
{
    __shared__ ushort Wh[128][32];
    __shared__ ushort Wo[128][32];
    __shared__ ushort Ih[128][32];
    __shared__ ushort Io[128][32];

    const int tid  = threadIdx.x;
    const int lane = tid & 63;
    const int wid  = tid >> 6;

    const int pixblk  = blockIdx.x;            // 0..127
    const int coutblk = blockIdx.y;            // 0..3
    const int b         = pixblk >> 3;
    const int pix_base  = (pixblk & 7) << 7;
    const int wr = (wid >> 1) * 64;            // wave cout-offset
    const int wc = (wid & 1) * 64;             // wave pix-offset
    const int rl = lane & 15;
    const int kg = (lane >> 4) << 3;

    // staging: wave wid owns tile rows [wid*32, wid*32+32); 2 issues per tensor
    const int r0 = wid << 5;
    const int rA = r0 + (lane >> 2);
    const int rB = rA + 16;
    const int ck = (lane & 3) << 3;            // 16-B chunk offset (elems)

    // W sources (tiled, contiguous per issue)
    const size_t wcb = (size_t)coutblk * 144 * 4096;
    const ushort* wAh = wt2hi + wcb + rA * 32 + ck;
    const ushort* wBh = wt2hi + wcb + rB * 32 + ck;
    const ushort* wAl = wt2lo + wcb + rA * 32 + ck;
    const ushort* wBl = wt2lo + wcb + rB * 32 + ck;

    // I sources (halo image, per-pixel rows)
    const size_t ibase = (size_t)b * 34 * 34 * 512;
    const int gpA = pix_base + rA, gpB = pix_base + rB;
    const int pAoff = ((gpA >> 5) * 34 + (gpA & 31)) * 512 + ck;
    const int pBoff = ((gpB >> 5) * 34 + (gpB & 31)) * 512 + ck;
    const ushort* iAh = ihi + ibase + pAoff;
    const ushort* iBh = ihi + ibase + pBoff;
    const ushort* iAl = ilo + ibase + pAoff;
    const ushort* iBl = ilo + ibase + pBoff;

    // wave-uniform LDS bases
    ushort* lWhA = &Wh[r0][0];      ushort* lWhB = &Wh[r0 + 16][0];
    ushort* lWoA = &Wo[r0][0];      ushort* lWoB = &Wo[r0 + 16][0];
    ushort* lIhA = &Ih[r0][0];      ushort* lIhB = &Ih[r0 + 16][0];
    ushort* lIoA = &Io[r0][0];      ushort* lIoB = &Io[r0 + 16][0];

    const float d0 = dn[b * 3 + 0];
    const float d1 = dn[b * 3 + 1];
    const float d2 = dn[b * 3 + 2];

    f32x4 acc[4][4];
    #pragma unroll
    for (int i = 0; i < 4; ++i)
        #pragma unroll
        for (int j = 0; j < 4; ++j) acc[i][j] = (f32x4)0.f;

    int step = 0;
    for (int seg = 0; seg < 3; ++seg) {
        for (int s = 0; s < 48; ++s, ++step) {
            const int k0  = step << 5;
            const int khw = k0 >> 9;                      // 0..8
            const int kh  = khw >= 6 ? 2 : (khw >= 3 ? 1 : 0);
            const int kw  = khw - kh * 3;
            const int soff = (kh * 34 + kw) * 512 + (k0 & 511);
            const int wst  = step << 12;                  // step*4096 elems

            __syncthreads();                 // prev reads done before overwrite
            gld16(wAh + wst, lWhA);
            gld16(wBh + wst, lWhB);
            gld16(wAl + wst, lWoA);
            gld16(wBl + wst, lWoB);
            gld16(iAh + soff, lIhA);
            gld16(iBh + soff, lIhB);
            gld16(iAl + soff, lIoA);
            gld16(iBl + soff, lIoB);
            __syncthreads();                 // drains vmcnt -> tiles ready

            short8 wa[4], wl8[4], ia[4], il8[4];
            #pragma unroll
            for (int mi = 0; mi < 4; ++mi) {
                wa[mi]  = *(const short8*)&Wh[wr + mi * 16 + rl][kg];
                wl8[mi] = *(const short8*)&Wo[wr + mi * 16 + rl][kg];
            }
            #pragma unroll
            for (int ni = 0; ni < 4; ++ni) {
                ia[ni]  = *(const short8*)&Ih[wc + ni * 16 + rl][kg];
                il8[ni] = *(const short8*)&Io[wc + ni * 16 + rl][kg];
            }
            #pragma unroll
            for (int mi = 0; mi < 4; ++mi)
                #pragma unroll
                for (int ni = 0; ni < 4; ++ni) {
                    acc[mi][ni] = __builtin_amdgcn_mfma_f32_16x16x32_bf16(
                        wa[mi], ia[ni], acc[mi][ni], 0, 0, 0);
                    acc[mi][ni] = __builtin_amdgcn_mfma_f32_16x16x32_bf16(
                        wa[mi], il8[ni], acc[mi][ni], 0, 0, 0);
                    acc[mi][ni] = __builtin_amdgcn_mfma_f32_16x16x32_bf16(
                        wl8[mi], ia[ni], acc[mi][ni], 0, 0, 0);
                }
        }
        if (seg < 2) {
            const float rr = (seg == 0) ? (d0 / d1) : (d1 / d2);
            #pragma unroll
            for (int mi = 0; mi < 4; ++mi)
                #pragma unroll
                for (int ni = 0; ni < 4; ++ni) acc[mi][ni] *= rr;
        }
    }

    // epilogue: x d2, store (C/D: col=lane&15 -> pixel, row=(lane>>4)*4+reg -> cout)
    const int cout_base = coutblk << 7;
    #pragma unroll
    for (int mi = 0; mi < 4; ++mi) {
        const int crow = cout_base + wr + mi * 16 + ((lane >> 4) << 2);
        #pragma unroll
        for (int ni = 0; ni < 4; ++ni) {
            const int ccol = pix_base + wc + ni * 16 + (lane & 15);
            float* op = out + ((size_t)(b << 9) + crow) * 1024 + ccol;
            f32x4 c = acc[mi][ni];
            #pragma unroll
            for (int r = 0; r < 4; ++r)
                op[(size_t)r * 1024] = c[r] * d2;
        }
    }
}

extern "C" void kernel_launch(void* const* d_in, const int* in_sizes, int n_in,
                              void* d_out, int out_size, void* d_ws, size_t ws_size,
                              hipStream_t stream) {
    const float* img  = (const float*)d_in[0];   // [16][512][32][32]
    const float* wl   = (const float*)d_in[1];   // [16][512]
    const float* dk   = (const float*)d_in[2];   // [512][512]
    const float* bias = (const float*)d_in[3];   // [512]
    const float* cw   = (const float*)d_in[4];   // [3][3][512][512]
    float* out = (float*)d_out;

    float* style = (float*)d_ws;                           // 8192 f32
    float* S     = style + 8192;                           // 1536 f32
    float* dn    = S + 1536;                               // 48 f32
    ushort* wt2hi = (ushort*)((char*)d_ws + 65536);        // [4][144][128][32]
    ushort* wt2lo = wt2hi + (size_t)4 * 144 * 4096;
    ushort* ihi   = wt2lo + (size_t)4 * 144 * 4096;        // [16][34][34][512]
    ushort* ilo   = ihi   + (size_t)16 * 34 * 34 * 512;

    style_kernel<<<dim3(8, 16), 256, 0, stream>>>(wl, dk, bias, style);
    wsum_kernel<<<1536, 64, 0, stream>>>(cw, S);
    denom_kernel<<<48, 64, 0, stream>>>(S, style, dn);
    wsplit_kernel<<<dim3(72, 8), 256, 0, stream>>>(cw, wt2hi, wt2lo);
    isplit_kernel<<<dim3(34, 16), 256, 0, stream>>>(img, style, ihi, ilo);

    conv_gemm<<<dim3(128, 4), 256, 0, stream>>>(wt2hi, wt2lo, ihi, ilo, dn, out);
}